// Round 16
// baseline (324.268 us; speedup 1.0000x reference)
//
#include <hip/hip_runtime.h>
#include <hip/hip_bf16.h>

#define HH 1024
#define FF 4096
#define MTOT (8 * 2048)

typedef __attribute__((ext_vector_type(4))) float f32x4;
typedef __attribute__((ext_vector_type(8))) short bf16x8;

template<int I> struct IC { static constexpr int value = I; };

__device__ inline void async_load16(const void* g, void* l) {
    __builtin_amdgcn_global_load_lds(
        (const __attribute__((address_space(1))) unsigned int*)g,
        (__attribute__((address_space(3))) unsigned int*)l, 16, 0, 0);
}
__device__ inline unsigned lds_off(void* p) {
    return (unsigned)(size_t)(__attribute__((address_space(3))) char*)p;
}
template<int OFF>
__device__ inline bf16x8 dsr(unsigned addr) {
    bf16x8 r;
    asm volatile("ds_read_b128 %0, %1 offset:%2" : "=v"(r) : "v"(addr), "n"(OFF));
    return r;
}
// bare waits (no "memory" clobber)
#define SBAR()  __builtin_amdgcn_s_barrier()
template<int N>
__device__ inline void LGKM() {
    asm volatile("s_waitcnt lgkmcnt(%0)" :: "n"(N));
    __builtin_amdgcn_sched_barrier(0);   // rule 18
}
#define WAIT_VM4() asm volatile("s_waitcnt vmcnt(4)")
#define WAIT_VM0() asm volatile("s_waitcnt vmcnt(0)")

// A frags: 8 x ds_read_b128, frag stride 1024 B (16 rows x 64 B); buf stride 16384 B
template<int B>
__device__ inline void ldA8(bf16x8 (&d)[8], unsigned vA) {
    constexpr int O = B * 16384;
    d[0] = dsr<O + 0>(vA);    d[1] = dsr<O + 1024>(vA);
    d[2] = dsr<O + 2048>(vA); d[3] = dsr<O + 3072>(vA);
    d[4] = dsr<O + 4096>(vA); d[5] = dsr<O + 5120>(vA);
    d[6] = dsr<O + 6144>(vA); d[7] = dsr<O + 7168>(vA);
}
template<int B>
__device__ inline void ldB4(bf16x8 (&d)[4], unsigned vB) {
    constexpr int O = B * 16384;
    d[0] = dsr<O + 0>(vB);    d[1] = dsr<O + 1024>(vB);
    d[2] = dsr<O + 2048>(vB); d[3] = dsr<O + 3072>(vB);
}

// ---------------- dequant + transpose: q[K][N], scales[K/128][N] -> wt[N][K] bf16
__global__ void dequant_t_kernel(const int* __restrict__ q,
                                 const float* __restrict__ scales,
                                 __hip_bfloat16* __restrict__ wt,
                                 int K, int N)
{
    __shared__ float tile[32][33];
    const int n0 = blockIdx.x * 32, k0 = blockIdx.y * 32;
    const int tx = threadIdx.x, ty = threadIdx.y; // (32,8)
#pragma unroll
    for (int i = 0; i < 32; i += 8) {
        int k = k0 + ty + i, n = n0 + tx;
        float s = scales[(size_t)(k >> 7) * N + n];
        tile[ty + i][tx] = (float)(q[(size_t)k * N + n] - 128) * s;
    }
    __syncthreads();
#pragma unroll
    for (int i = 0; i < 32; i += 8) {
        int n = n0 + ty + i, k = k0 + tx;
        wt[(size_t)n * K + k] = __float2bfloat16(tile[tx][ty + i]);
    }
}

// ---------------- LayerNorm
__global__ __launch_bounds__(256)
void ln_kernel(const float* __restrict__ x, const float* __restrict__ gamma,
               const float* __restrict__ beta, __hip_bfloat16* __restrict__ hf,
               int m0)
{
    const int row = m0 + blockIdx.x;
    const float4 v = ((const float4*)(x + (size_t)row * HH))[threadIdx.x];
    float s  = v.x + v.y + v.z + v.w;
    float ss = v.x * v.x + v.y * v.y + v.z * v.z + v.w * v.w;
#pragma unroll
    for (int o = 32; o > 0; o >>= 1) { s += __shfl_down(s, o); ss += __shfl_down(ss, o); }
    __shared__ float red[8];
    const int wid = threadIdx.x >> 6, lane = threadIdx.x & 63;
    if (lane == 0) { red[wid] = s; red[4 + wid] = ss; }
    __syncthreads();
    if (threadIdx.x == 0) {
        red[0] = red[0] + red[1] + red[2] + red[3];
        red[4] = red[4] + red[5] + red[6] + red[7];
    }
    __syncthreads();
    const float mu   = red[0] * (1.f / HH);
    const float rstd = rsqrtf(red[4] * (1.f / HH) - mu * mu + 1e-5f);
    const float4 g = ((const float4*)gamma)[threadIdx.x];
    const float4 b = ((const float4*)beta)[threadIdx.x];
    float h0 = (v.x - mu) * rstd * g.x + b.x;
    float h1 = (v.y - mu) * rstd * g.y + b.y;
    float h2 = (v.z - mu) * rstd * g.z + b.z;
    float h3 = (v.w - mu) * rstd * g.w + b.w;
    __hip_bfloat16 t0 = __float2bfloat16(h0), t1 = __float2bfloat16(h1);
    __hip_bfloat16 t2 = __float2bfloat16(h2), t3 = __float2bfloat16(h3);
    ushort4 o;
    o.x = *(unsigned short*)&t0; o.y = *(unsigned short*)&t1;
    o.z = *(unsigned short*)&t2; o.w = *(unsigned short*)&t3;
    ((ushort4*)(hf + (size_t)blockIdx.x * HH))[threadIdx.x] = o;
}

// ---------------- 256x256 bf16 MFMA GEMM, BK=32 3-buffer ring, counted vmcnt(4)
// EPI=0: out = bf16( silu(acc + bias) )     EPI=1: out = resid + 0.5f*(acc+bias)  (f32)
template<int EPI, int KK>
__global__ __launch_bounds__(512, 2)
void gemm256(const __hip_bfloat16* __restrict__ A,
             const __hip_bfloat16* __restrict__ Bt,
             const float* __restrict__ bias,
             const float* __restrict__ resid,
             void* __restrict__ outv,
             int N, int nbx)
{
    // 128 KiB LDS. K-loop uses first 96 KiB:
    //   A bufs @ bytes 0 / 16384 / 32768 (each 256 rows x 64 B)
    //   B bufs @ bytes 49152 / 65536 / 81920
    // Epilogue reuses the full 128 KiB as before.
    __shared__ __align__(16) short SM[65536];
    constexpr int NT = KK >> 5;            // 32-wide K tiles (32 or 128)

    // ---- 2D supertile XCD swizzle (R15), m204 fallback
    const int nwg = (int)gridDim.x, b = (int)blockIdx.x;
    const int nby = nwg / nbx;
    int bx, by;
    if (((nwg & 255) == 0) && ((nbx & 3) == 0) && ((nby & 7) == 0)) {
        const int x = b & 7, p = b >> 3;
        const int s = (p >> 5) * 8 + x;
        const int t = p & 31;
        const int sbx = nbx >> 2;
        bx = (s % sbx) * 4 + (t & 3);
        by = (s / sbx) * 8 + (t >> 2);
    } else {
        const int q = nwg >> 3, r = nwg & 7;
        const int xcd = b & 7, pos = b >> 3;
        const int bid = (xcd < r) ? xcd * (q + 1) + pos
                                  : r * (q + 1) + (xcd - r) * q + pos;
        bx = bid % nbx; by = bid / nbx;
    }
    const int rowA0 = by * 256, colB0 = bx * 256;

    const int tid = (int)threadIdx.x;
    const int lane = tid & 63, wid = tid >> 6;
    const int wr = wid >> 2, wc = wid & 3;       // 2x4 wave grid
    const int lrow = lane & 15, kg = lane >> 4;

    // staging: thread t covers (row = t>>2 in 0..127, 16B slot = t&3); 2 row-halves
    const int srow = tid >> 2;
    const __hip_bfloat16* aSrc = A  + (size_t)(rowA0 + srow) * KK + (tid & 3) * 8;
    const __hip_bfloat16* bSrc = Bt + (size_t)(colB0 + srow) * KK + (tid & 3) * 8;
    short* aDst = SM + srow * 32 + (tid & 3) * 8;            // = SM + tid*8 (linear!)
    short* bDst = SM + 24576 + srow * 32 + (tid & 3) * 8;

    // ds_read bases: 64 B row stride; no swizzle (parity bit spreads banks)
    const unsigned asB = lds_off(SM);
    const unsigned vA = asB + (unsigned)((wr * 128 + lrow) * 64 + (kg << 4));
    const unsigned vB = asB + 49152u + (unsigned)((wc * 64 + lrow) * 64 + (kg << 4));

    auto stage = [&](int sb, int t) {             // one 32-K tile: 4 loads
        const __hip_bfloat16* sA = aSrc + (size_t)t * 32;
        short* dA = aDst + sb * 8192;
        async_load16(sA, dA);
        async_load16(sA + (size_t)128 * KK, dA + 4096);
        const __hip_bfloat16* sB = bSrc + (size_t)t * 32;
        short* dB = bDst + sb * 8192;
        async_load16(sB, dB);
        async_load16(sB + (size_t)128 * KK, dB + 4096);
    };

    f32x4 acc[8][4] = {};

    auto phase = [&](auto bc, int tstage) {
        constexpr int B = decltype(bc)::value;
        const bool st = (tstage < NT);
        if (st) stage((B + 2) % 3, tstage);
        bf16x8 a[8], bbf[4];
        ldB4<B>(bbf, vB);
        ldA8<B>(a, vA);
        LGKM<4>();                    // b0-3 + a0-3 landed (in-order DS retire)
        __builtin_amdgcn_s_setprio(1);
#pragma unroll
        for (int mi = 0; mi < 4; ++mi)
#pragma unroll
            for (int ni = 0; ni < 4; ++ni)
                acc[mi][ni] = __builtin_amdgcn_mfma_f32_16x16x32_bf16(
                    a[mi], bbf[ni], acc[mi][ni], 0, 0, 0);
        __builtin_amdgcn_s_setprio(0);
        LGKM<0>();                    // a4-7 landed
        __builtin_amdgcn_s_setprio(1);
#pragma unroll
        for (int mi = 4; mi < 8; ++mi)
#pragma unroll
            for (int ni = 0; ni < 4; ++ni)
                acc[mi][ni] = __builtin_amdgcn_mfma_f32_16x16x32_bf16(
                    a[mi], bbf[ni], acc[mi][ni], 0, 0, 0);
        __builtin_amdgcn_s_setprio(0);
        if (st) WAIT_VM4();           // retire PREVIOUS phase's loads only
        else    WAIT_VM0();           // tail: drain
        SBAR();
    };

    // prologue: tile0 -> buf0, tile1 -> buf1; retire tile0, keep tile1 in flight
    stage(0, 0); stage(1, 1);
    WAIT_VM4();
    SBAR();

    int t = 2, p = 0;
    for (; p + 3 <= NT; p += 3) {
        phase(IC<0>{}, t); ++t;
        phase(IC<1>{}, t); ++t;
        phase(IC<2>{}, t); ++t;
    }
    if (p < NT) { phase(IC<0>{}, t); ++t; ++p; }   // NT%3==2 for K=1024/4096
    if (p < NT) { phase(IC<1>{}, t); ++t; ++p; }
    WAIT_VM0();

    // -------- epilogue: LDS-staged, fully coalesced global writes (R15 verbatim)
    __syncthreads();

    if (EPI == 0) {
        short* smh = SM;
#pragma unroll
        for (int ni = 0; ni < 4; ++ni) {
            const int col = wc * 64 + ni * 16 + lrow;
            const float bv = bias[colB0 + col];
#pragma unroll
            for (int mi = 0; mi < 8; ++mi) {
#pragma unroll
                for (int j = 0; j < 4; ++j) {
                    const int rowl = wr * 128 + mi * 16 + kg * 4 + j;
                    const float v = acc[mi][ni][j] + bv;
                    const float sv = v / (1.f + __expf(-v));
                    const __hip_bfloat16 hb = __float2bfloat16(sv);
                    const int sidx = rowl * 256 + ((((col >> 3) ^ (rowl & 7)) << 3) | (col & 7));
                    smh[sidx] = *(const short*)&hb;
                }
            }
        }
        __syncthreads();
        __hip_bfloat16* yp = (__hip_bfloat16*)outv;
#pragma unroll
        for (int p2 = 0; p2 < 16; ++p2) {
            const int idx = p2 * 512 + tid;
            const int rowl = idx >> 5, s = idx & 31;
            const bf16x8 v8 = *(const bf16x8*)&smh[rowl * 256 + ((s ^ (rowl & 7)) << 3)];
            *(bf16x8*)(yp + (size_t)(rowA0 + rowl) * N + colB0 + s * 8) = v8;
        }
    } else {
        float* smf = (float*)SM;
        float* op = (float*)outv;
#pragma unroll
        for (int h = 0; h < 2; ++h) {
            if (wr == h) {
#pragma unroll
                for (int ni = 0; ni < 4; ++ni) {
                    const int col = wc * 64 + ni * 16 + lrow;
                    const float bv = bias[colB0 + col];
#pragma unroll
                    for (int mi = 0; mi < 8; ++mi) {
#pragma unroll
                        for (int j = 0; j < 4; ++j) {
                            const int rowl = mi * 16 + kg * 4 + j;   // 0..127
                            const float v = acc[mi][ni][j] + bv;
                            const int fidx = rowl * 256 +
                                ((((col >> 2) ^ (rowl & 7)) << 2) | (col & 3));
                            smf[fidx] = v;
                        }
                    }
                }
            }
            __syncthreads();
#pragma unroll
            for (int p2 = 0; p2 < 16; ++p2) {
                const int idx = p2 * 512 + tid;
                const int rowl = idx >> 6, s = idx & 63;
                const f32x4 v4 = *(const f32x4*)&smf[rowl * 256 + ((s ^ (rowl & 7)) << 2)];
                const size_t g = (size_t)(rowA0 + h * 128 + rowl) * N + colB0 + s * 4;
                const float4 rv = *(const float4*)&resid[g];
                float4 o4;
                o4.x = rv.x + 0.5f * v4[0];
                o4.y = rv.y + 0.5f * v4[1];
                o4.z = rv.z + 0.5f * v4[2];
                o4.w = rv.w + 0.5f * v4[3];
                *(float4*)&op[g] = o4;
            }
            __syncthreads();
        }
    }
}

extern "C" void kernel_launch(void* const* d_in, const int* in_sizes, int n_in,
                              void* d_out, int out_size, void* d_ws, size_t ws_size,
                              hipStream_t stream)
{
    const float* x      = (const float*)d_in[0];
    const float* gamma  = (const float*)d_in[1];
    const float* beta   = (const float*)d_in[2];
    const int*   fc1_q  = (const int*)d_in[3];
    const float* fc1_s  = (const float*)d_in[4];
    const float* fc1_b  = (const float*)d_in[5];
    const int*   fc2_q  = (const int*)d_in[6];
    const float* fc2_s  = (const float*)d_in[7];
    const float* fc2_b  = (const float*)d_in[8];
    float* out = (float*)d_out;

    char* ws = (char*)d_ws;
    __hip_bfloat16* w1t = (__hip_bfloat16*)ws;                            // [F][H]
    __hip_bfloat16* w2t = (__hip_bfloat16*)(ws + (size_t)FF * HH * 2);    // [H][F]
    char* dyn = ws + (size_t)2 * FF * HH * 2;
    const size_t avail = ws_size - (size_t)2 * FF * HH * 2;

    int MC = (int)(avail / ((size_t)(HH + FF) * 2));
    MC = (MC / 256) * 256;
    if (MC > MTOT) MC = MTOT;
    if (MC < 256)  MC = 256;

    __hip_bfloat16* hf_c = (__hip_bfloat16*)dyn;
    __hip_bfloat16* y_c  = (__hip_bfloat16*)(dyn + (size_t)MC * HH * 2);

    dequant_t_kernel<<<dim3(FF / 32, HH / 32), dim3(32, 8), 0, stream>>>(
        fc1_q, fc1_s, w1t, HH, FF);
    dequant_t_kernel<<<dim3(HH / 32, FF / 32), dim3(32, 8), 0, stream>>>(
        fc2_q, fc2_s, w2t, FF, HH);

    for (int m0 = 0; m0 < MTOT; m0 += MC) {
        const int mc = (MTOT - m0 < MC) ? (MTOT - m0) : MC;
        ln_kernel<<<mc, 256, 0, stream>>>(x, gamma, beta, hf_c, m0);
        gemm256<0, HH><<<dim3((FF / 256) * (mc / 256)), 512, 0, stream>>>(
            hf_c, w1t, fc1_b, nullptr, (void*)y_c, FF, FF / 256);
        gemm256<1, FF><<<dim3((HH / 256) * (mc / 256)), 512, 0, stream>>>(
            y_c, w2t, fc2_b, x + (size_t)m0 * HH, (void*)(out + (size_t)m0 * HH),
            HH, HH / 256);
    }
}

// Round 17
// 312.498 us; speedup vs baseline: 1.0377x; 1.0377x over previous
//
#include <hip/hip_runtime.h>
#include <hip/hip_bf16.h>

#define HH 1024
#define FF 4096
#define MTOT (8 * 2048)

typedef __attribute__((ext_vector_type(4))) float f32x4;
typedef __attribute__((ext_vector_type(8))) short bf16x8;

__device__ inline void async_load16(const void* g, void* l) {
    __builtin_amdgcn_global_load_lds(
        (const __attribute__((address_space(1))) unsigned int*)g,
        (__attribute__((address_space(3))) unsigned int*)l, 16, 0, 0);
}
__device__ inline unsigned lds_off(void* p) {
    return (unsigned)(size_t)(__attribute__((address_space(3))) char*)p;
}
template<int OFF>
__device__ inline bf16x8 dsr(unsigned addr) {
    bf16x8 r;
    asm volatile("ds_read_b128 %0, %1 offset:%2" : "=v"(r) : "v"(addr), "n"(OFF));
    return r;
}
// bare waits (no "memory" clobber)
#define SBAR()  __builtin_amdgcn_s_barrier()
#define LGKM0() do { asm volatile("s_waitcnt lgkmcnt(0)"); \
                     __builtin_amdgcn_sched_barrier(0); } while (0)
#define WAIT_VM0() asm volatile("s_waitcnt vmcnt(0)")

// ds_read fragment loads: base VGPR + compile-time offset only
template<int BUF, int MH>
__device__ inline void ldA(bf16x8 (&d)[4][2], unsigned vA0, unsigned vA1) {
    constexpr int B = BUF * 32768 + MH * 8192;
    d[0][0] = dsr<B + 0>(vA0);     d[0][1] = dsr<B + 0>(vA1);
    d[1][0] = dsr<B + 2048>(vA0);  d[1][1] = dsr<B + 2048>(vA1);
    d[2][0] = dsr<B + 4096>(vA0);  d[2][1] = dsr<B + 4096>(vA1);
    d[3][0] = dsr<B + 6144>(vA0);  d[3][1] = dsr<B + 6144>(vA1);
}
template<int BUF, int NH>
__device__ inline void ldB(bf16x8 (&d)[2][2], unsigned vB0, unsigned vB1) {
    constexpr int B = BUF * 32768 + NH * 4096;
    d[0][0] = dsr<B + 0>(vB0);     d[0][1] = dsr<B + 0>(vB1);
    d[1][0] = dsr<B + 2048>(vB0);  d[1][1] = dsr<B + 2048>(vB1);
}

// ---------------- dequant + transpose: q[K][N], scales[K/128][N] -> wt[N][K] bf16
__global__ void dequant_t_kernel(const int* __restrict__ q,
                                 const float* __restrict__ scales,
                                 __hip_bfloat16* __restrict__ wt,
                                 int K, int N)
{
    __shared__ float tile[32][33];
    const int n0 = blockIdx.x * 32, k0 = blockIdx.y * 32;
    const int tx = threadIdx.x, ty = threadIdx.y; // (32,8)
#pragma unroll
    for (int i = 0; i < 32; i += 8) {
        int k = k0 + ty + i, n = n0 + tx;
        float s = scales[(size_t)(k >> 7) * N + n];
        tile[ty + i][tx] = (float)(q[(size_t)k * N + n] - 128) * s;
    }
    __syncthreads();
#pragma unroll
    for (int i = 0; i < 32; i += 8) {
        int n = n0 + ty + i, k = k0 + tx;
        wt[(size_t)n * K + k] = __float2bfloat16(tile[tx][ty + i]);
    }
}

// ---------------- LayerNorm
__global__ __launch_bounds__(256)
void ln_kernel(const float* __restrict__ x, const float* __restrict__ gamma,
               const float* __restrict__ beta, __hip_bfloat16* __restrict__ hf,
               int m0)
{
    const int row = m0 + blockIdx.x;
    const float4 v = ((const float4*)(x + (size_t)row * HH))[threadIdx.x];
    float s  = v.x + v.y + v.z + v.w;
    float ss = v.x * v.x + v.y * v.y + v.z * v.z + v.w * v.w;
#pragma unroll
    for (int o = 32; o > 0; o >>= 1) { s += __shfl_down(s, o); ss += __shfl_down(ss, o); }
    __shared__ float red[8];
    const int wid = threadIdx.x >> 6, lane = threadIdx.x & 63;
    if (lane == 0) { red[wid] = s; red[4 + wid] = ss; }
    __syncthreads();
    if (threadIdx.x == 0) {
        red[0] = red[0] + red[1] + red[2] + red[3];
        red[4] = red[4] + red[5] + red[6] + red[7];
    }
    __syncthreads();
    const float mu   = red[0] * (1.f / HH);
    const float rstd = rsqrtf(red[4] * (1.f / HH) - mu * mu + 1e-5f);
    const float4 g = ((const float4*)gamma)[threadIdx.x];
    const float4 b = ((const float4*)beta)[threadIdx.x];
    float h0 = (v.x - mu) * rstd * g.x + b.x;
    float h1 = (v.y - mu) * rstd * g.y + b.y;
    float h2 = (v.z - mu) * rstd * g.z + b.z;
    float h3 = (v.w - mu) * rstd * g.w + b.w;
    __hip_bfloat16 t0 = __float2bfloat16(h0), t1 = __float2bfloat16(h1);
    __hip_bfloat16 t2 = __float2bfloat16(h2), t3 = __float2bfloat16(h3);
    ushort4 o;
    o.x = *(unsigned short*)&t0; o.y = *(unsigned short*)&t1;
    o.z = *(unsigned short*)&t2; o.w = *(unsigned short*)&t3;
    ((ushort4*)(hf + (size_t)blockIdx.x * HH))[threadIdx.x] = o;
}

// ---------------- 256x256 bf16 MFMA GEMM, R11 rhythm + 2D supertile XCD swizzle
// EPI=0: out = bf16( silu(acc + bias) )     EPI=1: out = resid + 0.5f*(acc+bias)  (f32)
template<int EPI, int KK>
__global__ __launch_bounds__(512, 2)
void gemm256(const __hip_bfloat16* __restrict__ A,
             const __hip_bfloat16* __restrict__ Bt,
             const float* __restrict__ bias,
             const float* __restrict__ resid,
             void* __restrict__ outv,
             int N, int nbx)
{
    // unified 128 KiB LDS: As = SM[0..32767], Bs = SM[32768..65535] (shorts)
    __shared__ __align__(16) short SM[65536];
    constexpr int NT = KK >> 6;

    // ---- block -> (bx,by): 2D supertile XCD swizzle (4 bx x 8 by = 32 blocks/XCD
    // concurrent working set = 4 B-panels + 8 A-panels, L2-resident). Fallback: m204.
    const int nwg = (int)gridDim.x, b = (int)blockIdx.x;
    const int nby = nwg / nbx;
    int bx, by;
    if (((nwg & 255) == 0) && ((nbx & 3) == 0) && ((nby & 7) == 0)) {
        const int x = b & 7, p = b >> 3;
        const int s = (p >> 5) * 8 + x;      // supertile id for this XCD
        const int t = p & 31;                // index within 32-block supertile
        const int sbx = nbx >> 2;            // supertiles across bx
        bx = (s % sbx) * 4 + (t & 3);
        by = (s / sbx) * 8 + (t >> 2);
    } else {
        const int q = nwg >> 3, r = nwg & 7;
        const int xcd = b & 7, pos = b >> 3;
        const int bid = (xcd < r) ? xcd * (q + 1) + pos
                                  : r * (q + 1) + (xcd - r) * q + pos;
        bx = bid % nbx; by = bid / nbx;
    }
    const int rowA0 = by * 256, colB0 = bx * 256;

    const int tid = (int)threadIdx.x;
    const int lane = tid & 63, wid = tid >> 6;
    const int wr = wid >> 2, wc = wid & 3;       // 2x4 wave grid
    const int lrow = lane & 15, kg = lane >> 4;
    const int swz = lrow & 7;

    // staging: thread t covers (row = t/8, 16B slot = t%8), source pre-inverse-swizzled
    const int srow = tid >> 3;
    const int sgs  = (tid & 7) ^ (srow & 7);
    const __hip_bfloat16* aSrc = A  + (size_t)(rowA0 + srow) * KK + sgs * 8;
    const __hip_bfloat16* bSrc = Bt + (size_t)(colB0 + srow) * KK + sgs * 8;
    short* aDst = SM + srow * 64 + (tid & 7) * 8;
    short* bDst = SM + 32768 + srow * 64 + (tid & 7) * 8;

    // precomputed ds_read bases
    const unsigned asB = lds_off(SM);
    const unsigned k0off = (unsigned)((kg ^ swz) << 4);
    const unsigned k1off = (unsigned)(((4 + kg) ^ swz) << 4);
    const unsigned vA0 = asB + (unsigned)((wr * 128 + lrow) * 128) + k0off;
    const unsigned vA1 = asB + (unsigned)((wr * 128 + lrow) * 128) + k1off;
    const unsigned vB0 = asB + 65536u + (unsigned)((wc * 64 + lrow) * 128) + k0off;
    const unsigned vB1 = asB + 65536u + (unsigned)((wc * 64 + lrow) * 128) + k1off;

    auto stA = [&](int buf, int t, int half) {    // one A half-tile: 2 loads
        const size_t ko = (size_t)t * 64;
        short* d = aDst + buf * 16384 + half * 8192;
        const __hip_bfloat16* s0 = aSrc + (size_t)(half * 128) * KK + ko;
        async_load16(s0, d);
        async_load16(s0 + (size_t)64 * KK, d + 4096);
    };
    auto stB = [&](int buf, int t, int half) {    // one B half-tile: 2 loads
        const size_t ko = (size_t)t * 64;
        short* d = bDst + buf * 16384 + half * 8192;
        const __hip_bfloat16* s0 = bSrc + (size_t)(half * 128) * KK + ko;
        async_load16(s0, d);
        async_load16(s0 + (size_t)64 * KK, d + 4096);
    };

    f32x4 acc[8][4] = {};
    auto mf = [&](const bf16x8 (&a)[4][2], const bf16x8 (&bb)[2][2], int mh, int nh) {
        __builtin_amdgcn_s_setprio(1);
#pragma unroll
        for (int ks = 0; ks < 2; ++ks)
#pragma unroll
            for (int m2 = 0; m2 < 4; ++m2)
#pragma unroll
                for (int n2 = 0; n2 < 2; ++n2)
                    acc[mh * 4 + m2][nh * 2 + n2] =
                        __builtin_amdgcn_mfma_f32_16x16x32_bf16(
                            a[m2][ks], bb[n2][ks], acc[mh * 4 + m2][nh * 2 + n2], 0, 0, 0);
        __builtin_amdgcn_s_setprio(0);
    };

    // -------- prologue: buf0 <- tile 0 (16 loads); drain; barrier
    stA(0, 0, 0); stA(0, 0, 1); stB(0, 0, 0); stB(0, 0, 1);
    WAIT_VM0();
    SBAR();

    bf16x8 a0[4][2], a1[4][2], b0[2][2], b1[2][2];
    const int NI = NT >> 1;
    for (int i = 0; i < NI; ++i) {
        const int c = 2 * i, n = 2 * i + 1;
        // ================= T1: tile c (buf0); stage buf1 <- tile n =================
        stA(1, n, 0); stA(1, n, 1); stB(1, n, 0); stB(1, n, 1);
        ldA<0, 0>(a0, vA0, vA1);   // reads 1-8
        ldB<0, 0>(b0, vB0, vB1);   // reads 9-12
        ldB<0, 1>(b1, vB0, vB1);   // reads 13-16
        ldA<0, 1>(a1, vA0, vA1);   // reads 17-24
        LGKM0();
        mf(a0, b0, 0, 0);
        mf(a0, b1, 0, 1);
        mf(a1, b0, 1, 0);
        mf(a1, b1, 1, 1);
        WAIT_VM0();                 // staged loads (issued ~whole phase ago) done
        SBAR();                     // all waves drained -> buf1 readable, buf0 free
        // ================= T2: tile n (buf1); stage buf0 <- tile c+2 ===============
        if (i < NI - 1) { stA(0, c + 2, 0); stA(0, c + 2, 1);
                          stB(0, c + 2, 0); stB(0, c + 2, 1); }
        ldA<1, 0>(a0, vA0, vA1);
        ldB<1, 0>(b0, vB0, vB1);
        ldB<1, 1>(b1, vB0, vB1);
        ldA<1, 1>(a1, vA0, vA1);
        LGKM0();
        mf(a0, b0, 0, 0);
        mf(a0, b1, 0, 1);
        mf(a1, b0, 1, 0);
        mf(a1, b1, 1, 1);
        WAIT_VM0();
        SBAR();
    }

    // -------- epilogue: LDS-staged, fully coalesced global writes --------
    __syncthreads();   // real fence: all waves done with SM before restaging

    if (EPI == 0) {
        // bf16 tile 256 rows x 512 B = 128 KiB, XOR-slot swizzle (8-col slots)
        short* smh = SM;
#pragma unroll
        for (int ni = 0; ni < 4; ++ni) {
            const int col = wc * 64 + ni * 16 + lrow;
            const float bv = bias[colB0 + col];
#pragma unroll
            for (int mi = 0; mi < 8; ++mi) {
#pragma unroll
                for (int j = 0; j < 4; ++j) {
                    const int rowl = wr * 128 + mi * 16 + kg * 4 + j;
                    const float v = acc[mi][ni][j] + bv;
                    const float sv = v / (1.f + __expf(-v));
                    const __hip_bfloat16 hb = __float2bfloat16(sv);
                    const int sidx = rowl * 256 + ((((col >> 3) ^ (rowl & 7)) << 3) | (col & 7));
                    smh[sidx] = *(const short*)&hb;
                }
            }
        }
        __syncthreads();
        __hip_bfloat16* yp = (__hip_bfloat16*)outv;
#pragma unroll
        for (int p = 0; p < 16; ++p) {
            const int idx = p * 512 + tid;
            const int rowl = idx >> 5, s = idx & 31;
            const bf16x8 v8 = *(const bf16x8*)&smh[rowl * 256 + ((s ^ (rowl & 7)) << 3)];
            *(bf16x8*)(yp + (size_t)(rowA0 + rowl) * N + colB0 + s * 8) = v8;
        }
    } else {
        // f32 tile in two row-halves of 128 x 1024 B = 128 KiB each
        float* smf = (float*)SM;
        float* op = (float*)outv;
#pragma unroll
        for (int h = 0; h < 2; ++h) {
            if (wr == h) {
#pragma unroll
                for (int ni = 0; ni < 4; ++ni) {
                    const int col = wc * 64 + ni * 16 + lrow;
                    const float bv = bias[colB0 + col];
#pragma unroll
                    for (int mi = 0; mi < 8; ++mi) {
#pragma unroll
                        for (int j = 0; j < 4; ++j) {
                            const int rowl = mi * 16 + kg * 4 + j;   // 0..127
                            const float v = acc[mi][ni][j] + bv;
                            const int fidx = rowl * 256 +
                                ((((col >> 2) ^ (rowl & 7)) << 2) | (col & 3));
                            smf[fidx] = v;
                        }
                    }
                }
            }
            __syncthreads();
#pragma unroll
            for (int p = 0; p < 16; ++p) {
                const int idx = p * 512 + tid;
                const int rowl = idx >> 6, s = idx & 63;
                const f32x4 v4 = *(const f32x4*)&smf[rowl * 256 + ((s ^ (rowl & 7)) << 2)];
                const size_t g = (size_t)(rowA0 + h * 128 + rowl) * N + colB0 + s * 4;
                const float4 rv = *(const float4*)&resid[g];
                float4 o4;
                o4.x = rv.x + 0.5f * v4[0];
                o4.y = rv.y + 0.5f * v4[1];
                o4.z = rv.z + 0.5f * v4[2];
                o4.w = rv.w + 0.5f * v4[3];
                *(float4*)&op[g] = o4;
            }
            __syncthreads();
        }
    }
}

extern "C" void kernel_launch(void* const* d_in, const int* in_sizes, int n_in,
                              void* d_out, int out_size, void* d_ws, size_t ws_size,
                              hipStream_t stream)
{
    const float* x      = (const float*)d_in[0];
    const float* gamma  = (const float*)d_in[1];
    const float* beta   = (const float*)d_in[2];
    const int*   fc1_q  = (const int*)d_in[3];
    const float* fc1_s  = (const float*)d_in[4];
    const float* fc1_b  = (const float*)d_in[5];
    const int*   fc2_q  = (const int*)d_in[6];
    const float* fc2_s  = (const float*)d_in[7];
    const float* fc2_b  = (const float*)d_in[8];
    float* out = (float*)d_out;

    char* ws = (char*)d_ws;
    __hip_bfloat16* w1t = (__hip_bfloat16*)ws;                            // [F][H]
    __hip_bfloat16* w2t = (__hip_bfloat16*)(ws + (size_t)FF * HH * 2);    // [H][F]
    char* dyn = ws + (size_t)2 * FF * HH * 2;
    const size_t avail = ws_size - (size_t)2 * FF * HH * 2;

    int MC = (int)(avail / ((size_t)(HH + FF) * 2));
    MC = (MC / 256) * 256;
    if (MC > MTOT) MC = MTOT;
    if (MC < 256)  MC = 256;

    __hip_bfloat16* hf_c = (__hip_bfloat16*)dyn;
    __hip_bfloat16* y_c  = (__hip_bfloat16*)(dyn + (size_t)MC * HH * 2);

    dequant_t_kernel<<<dim3(FF / 32, HH / 32), dim3(32, 8), 0, stream>>>(
        fc1_q, fc1_s, w1t, HH, FF);
    dequant_t_kernel<<<dim3(HH / 32, FF / 32), dim3(32, 8), 0, stream>>>(
        fc2_q, fc2_s, w2t, FF, HH);

    for (int m0 = 0; m0 < MTOT; m0 += MC) {
        const int mc = (MTOT - m0 < MC) ? (MTOT - m0) : MC;
        ln_kernel<<<mc, 256, 0, stream>>>(x, gamma, beta, hf_c, m0);
        gemm256<0, HH><<<dim3((FF / 256) * (mc / 256)), 512, 0, stream>>>(
            hf_c, w1t, fc1_b, nullptr, (void*)y_c, FF, FF / 256);
        gemm256<1, FF><<<dim3((HH / 256) * (mc / 256)), 512, 0, stream>>>(
            y_c, w2t, fc2_b, x + (size_t)m0 * HH, (void*)(out + (size_t)m0 * HH),
            HH, HH / 256);
    }
}